// Round 15
// baseline (584.253 us; speedup 1.0000x reference)
//
#include <hip/hip_runtime.h>
#include <cstdint>
#include <cstddef>

typedef __attribute__((ext_vector_type(8))) short short8;
typedef __attribute__((ext_vector_type(4))) float f32x4;

#define MFMA16(a,b,c) __builtin_amdgcn_mfma_f32_16x16x32_bf16((a),(b),(c),0,0,0)

// ---------------- ws layout (bytes) ----------------
#define OFF_QWT   0ull
#define OFF_KWT   16777216ull
#define OFF_VWT   33554432ull
#define OFF_O     50331648ull
#define OFF_A     83886080ull
#define OFF_H1ACC 100663296ull
#define OFF_H1ACT 110903296ull
#define OFF_W2B   116146176ull
#define OFF_H2ACC 116801536ull
#define OFF_ROWS  116932608ull
#define OFF_OSTAT 116940800ull
#define OFF_W1RS  116941312ull   // f32 [5056]

__device__ __forceinline__ unsigned short f2b(float x) {
  union { float f; unsigned int u; } v; v.f = x;
  unsigned int r = v.u + 0x7fffu + ((v.u >> 16) & 1u);
  return (unsigned short)(r >> 16);
}

__device__ __forceinline__ float b2f(unsigned int u16) {
  union { unsigned int u; float f; } v; v.u = u16 << 16;
  return v.f;
}

__device__ __forceinline__ unsigned int cvtpk(float a, float b) {
  unsigned int r;
  asm("v_cvt_pk_bf16_f32 %0, %1, %2" : "=v"(r) : "v"(a), "v"(b));
  return r;
}

__device__ __forceinline__ void gload16(const void* g, void* l) {
  __builtin_amdgcn_global_load_lds((const __attribute__((address_space(1))) unsigned int*)g,
                                   (__attribute__((address_space(3))) unsigned int*)l,
                                   16, 0, 0);
}

// zero h1acc/h2acc/w1rs + convert W2 -> bf16 padded, one launch
__global__ __launch_bounds__(256) void k_prep(float* __restrict__ p1, int n1,
                                              float* __restrict__ p2, int n2,
                                              float* __restrict__ p3, int n3,
                                              const float* __restrict__ W2,
                                              unsigned short* __restrict__ w2b) {
  int i = blockIdx.x * 256 + threadIdx.x;
  int nz2 = n1 + n2;
  int nz = nz2 + n3;
  int total = nz + 64 * 1280;
  for (; i < total; i += gridDim.x * 256) {
    if (i < n1) p1[i] = 0.f;
    else if (i < nz2) p2[i - n1] = 0.f;
    else if (i < nz) p3[i - nz2] = 0.f;
    else {
      int j = i - nz;
      int n = j / 1280;
      int o4 = (j - n * 1280) * 4;
      unsigned int lo = 0, hi = 0;
      if (o4 < 5000) {
        lo = f2b(W2[n * 5000 + o4]) | ((unsigned int)f2b(W2[n * 5000 + o4 + 1]) << 16);
        hi = f2b(W2[n * 5000 + o4 + 2]) | ((unsigned int)f2b(W2[n * 5000 + o4 + 3]) << 16);
      }
      *(uint2*)(w2b + (size_t)n * 5120 + o4) = make_uint2(lo, hi);
    }
  }
}

__global__ __launch_bounds__(256) void k_proj3(const float* __restrict__ qx,
    const float* __restrict__ kx, const float* __restrict__ vx,
    const float* __restrict__ Wq, const float* __restrict__ Wk, const float* __restrict__ Wv,
    const float* __restrict__ bqv, const float* __restrict__ bkv, const float* __restrict__ bvv,
    float* __restrict__ proj, float* __restrict__ rowsb)
{
  __shared__ float xs[124][32];
  __shared__ float Wsh[124 * 124];
  const int sc = blockIdx.x, b = blockIdx.y, t = blockIdx.z;
  const float* x = (t == 0) ? qx : (t == 1) ? kx : vx;
  const float* W = (t == 0) ? Wq : (t == 1) ? Wk : Wv;
  const float* bias = (t == 0) ? bqv : (t == 1) ? bkv : bvv;
  float* out = proj + (size_t)t * 1048576;
  float* rowstat = rowsb + t * 248;
  const int s0 = sc * 32;
  const int tid = threadIdx.x;
  const float* xb = x + (size_t)b * 124 * 256;
  for (int e = tid; e < 15376; e += 256) Wsh[e] = W[e];
  for (int e = tid; e < 3968; e += 256) {
    int f = e >> 5, s = e & 31;
    xs[f][s] = xb[f * 256 + s0 + s];
  }
  __syncthreads();
  float* ob = out + (size_t)b * 124 * 256;
  for (int base = 0; base < 3968; base += 256) {
    int e = base + tid;
    bool valid = e < 3968;
    int g = valid ? (e >> 5) : 0;
    int s = e & 31;
    float acc = 0.f;
    if (valid) {
      acc = bias[g];
      const float* wr = Wsh + g * 124;
      #pragma unroll 4
      for (int f = 0; f < 124; ++f) acc += wr[f] * xs[f][s];
      ob[g * 256 + s0 + s] = acc;
    }
    float v1 = valid ? acc : 0.f;
    float v2 = v1 * v1;
    #pragma unroll
    for (int m = 1; m < 32; m <<= 1) { v1 += __shfl_xor(v1, m); v2 += __shfl_xor(v2, m); }
    if (valid && (tid & 31) == 0) {
      atomicAdd(&rowstat[g * 2], v1);
      atomicAdd(&rowstat[g * 2 + 1], v2);
    }
  }
}

// winnorm + inline headstats
__global__ __launch_bounds__(256) void k_winnorm(const float* __restrict__ proj,
    const float* __restrict__ rows,
    const float* __restrict__ gq, const float* __restrict__ gk, const float* __restrict__ gv,
    const float* __restrict__ beq, const float* __restrict__ bek, const float* __restrict__ bev,
    unsigned short* __restrict__ outq, unsigned short* __restrict__ outk,
    unsigned short* __restrict__ outv)
{
  __shared__ float T[64][65];
  __shared__ float ssh[2];
  const int h = blockIdx.x, b = blockIdx.y, t = blockIdx.z;
  const int tid = threadIdx.x;
  if (tid == 0) {
    const float* rp = rows + t * 248;
    float s = 0.f, q = 0.f;
    for (int j = 0; j < 64; ++j) {
      s += rp[(h * 4 + j) * 2];
      q += rp[(h * 4 + j) * 2 + 1];
    }
    const float N = 524288.f;
    float mean = s / N;
    float var = q / N - mean * mean;
    float gamma = (t == 0 ? gq[h] : (t == 1 ? gk[h] : gv[h]));
    float beta  = (t == 0 ? beq[h] : (t == 1 ? bek[h] : bev[h]));
    float scale = gamma * rsqrtf(var + 1e-5f);
    ssh[0] = scale;
    ssh[1] = beta - mean * scale;
  }
  __syncthreads();
  const float scale = ssh[0], shift = ssh[1];
  const float* in = proj + (size_t)t * 1048576 + (size_t)(b * 124 + h * 4) * 256;
  const size_t obase = (size_t)(b * 16 + h) * 16384;
  if (t < 2) {
    unsigned short* out = (t == 0 ? outq : outk) + obase;
    for (int sc = 0; sc < 4; ++sc) {
      const int s0 = sc * 64;
      for (int e = tid; e < 1024; e += 256) {
        int g = e >> 4, qq = e & 15;
        float4 val = *(const float4*)(in + g * 256 + s0 + qq * 4);
        T[g][qq * 4 + 0] = val.x * scale + shift;
        T[g][qq * 4 + 1] = val.y * scale + shift;
        T[g][qq * 4 + 2] = val.z * scale + shift;
        T[g][qq * 4 + 3] = val.w * scale + shift;
      }
      __syncthreads();
      for (int e = tid; e < 512; e += 256) {
        int sl = e >> 3, j0 = (e & 7) * 8;
        unsigned int pk[4];
        #pragma unroll
        for (int jj = 0; jj < 4; ++jj) {
          unsigned int a0 = f2b(T[j0 + jj * 2][sl]);
          unsigned int a1 = f2b(T[j0 + jj * 2 + 1][sl]);
          pk[jj] = a0 | (a1 << 16);
        }
        *(uint4*)(out + (s0 + sl) * 64 + j0) = make_uint4(pk[0], pk[1], pk[2], pk[3]);
      }
      __syncthreads();
    }
  } else {
    unsigned short* out = outv + obase;
    for (int e = tid * 4; e < 16384; e += 1024) {
      float4 val = *(const float4*)(in + e);
      unsigned int lo = f2b(val.x * scale + shift) | ((unsigned int)f2b(val.y * scale + shift) << 16);
      unsigned int hi = f2b(val.z * scale + shift) | ((unsigned int)f2b(val.w * scale + shift) << 16);
      *(uint2*)(out + e) = make_uint2(lo, hi);
    }
  }
}

__global__ __launch_bounds__(256) void k_attn(const unsigned short* __restrict__ qwt,
    const unsigned short* __restrict__ kwt, const unsigned short* __restrict__ vwt,
    unsigned short* __restrict__ ob, float* __restrict__ ostats)
{
  __shared__ __align__(16) unsigned short P[4][16 * 256];
  __shared__ float redbuf[8];
  const int h = blockIdx.x, b = blockIdx.y;
  const int bh = b * 16 + h;
  const unsigned short* Q = qwt + (size_t)bh * 16384;
  const unsigned short* K = kwt + (size_t)bh * 16384;
  const unsigned short* V = vwt + (size_t)bh * 16384;
  const int tid = threadIdx.x, w = tid >> 6, l = tid & 63;
  const int lr = l & 15, lg = l >> 4;
  char* Pw = (char*)&P[w][0];
  float s1 = 0.f, s2 = 0.f;
  for (int ch = 0; ch < 4; ++ch) {
    const int i0 = w * 64 + ch * 16;
    short8 qf0 = *(const short8*)(Q + (i0 + lr) * 64 + lg * 8);
    short8 qf1 = *(const short8*)(Q + (i0 + lr) * 64 + 32 + lg * 8);
    f32x4 S[16];
    #pragma unroll
    for (int jt = 0; jt < 16; ++jt) {
      const unsigned short* Kr = K + (jt * 16 + lr) * 64 + lg * 8;
      short8 kf0 = *(const short8*)(Kr);
      short8 kf1 = *(const short8*)(Kr + 32);
      f32x4 a = {0.f, 0.f, 0.f, 0.f};
      a = MFMA16(qf0, kf0, a);
      a = MFMA16(qf1, kf1, a);
      S[jt] = a;
    }
    float mx[4], sm[4], rinv[4];
    #pragma unroll
    for (int r = 0; r < 4; ++r) {
      float m = S[0][r];
      #pragma unroll
      for (int jt = 1; jt < 16; ++jt) m = fmaxf(m, S[jt][r]);
      m = fmaxf(m, __shfl_xor(m, 1));
      m = fmaxf(m, __shfl_xor(m, 2));
      m = fmaxf(m, __shfl_xor(m, 4));
      m = fmaxf(m, __shfl_xor(m, 8));
      mx[r] = m; sm[r] = 0.f;
    }
    #pragma unroll
    for (int jt = 0; jt < 16; ++jt) {
      #pragma unroll
      for (int r = 0; r < 4; ++r) {
        float p = exp2f((S[jt][r] - mx[r]) * 0.18033688011112042f);
        sm[r] += p;
        S[jt][r] = p;
      }
    }
    #pragma unroll
    for (int r = 0; r < 4; ++r) {
      float s = sm[r];
      s += __shfl_xor(s, 1); s += __shfl_xor(s, 2);
      s += __shfl_xor(s, 4); s += __shfl_xor(s, 8);
      rinv[r] = 1.0f / s;
    }
    #pragma unroll
    for (int jt = 0; jt < 16; ++jt) {
      #pragma unroll
      for (int r = 0; r < 4; ++r) {
        int rr = lg * 4 + r;
        int c = jt * 16 + lr;
        int off = rr * 512 + ((c * 2) ^ ((rr & 7) << 4));
        *(unsigned short*)(Pw + off) = f2b(S[jt][r]);
      }
    }
    asm volatile("s_waitcnt lgkmcnt(0)" ::: "memory");
    f32x4 O[4];
    #pragma unroll
    for (int nt = 0; nt < 4; ++nt) O[nt] = (f32x4){0.f, 0.f, 0.f, 0.f};
    #pragma unroll
    for (int js = 0; js < 8; ++js) {
      int off = lr * 512 + (((js * 32 + lg * 8) * 2) ^ ((lr & 7) << 4));
      short8 pf = *(const short8*)(Pw + off);
      #pragma unroll
      for (int nt = 0; nt < 4; ++nt) {
        short8 vf = *(const short8*)(V + (nt * 16 + lr) * 256 + js * 32 + lg * 8);
        O[nt] = MFMA16(pf, vf, O[nt]);
      }
    }
    unsigned short* orow = ob + (size_t)bh * 16384 + (size_t)i0 * 64;
    #pragma unroll
    for (int nt = 0; nt < 4; ++nt) {
      #pragma unroll
      for (int r = 0; r < 4; ++r) {
        float val = O[nt][r] * rinv[r];
        orow[(lg * 4 + r) * 64 + nt * 16 + lr] = f2b(val);
        s1 += val; s2 += val * val;
      }
    }
  }
  #pragma unroll
  for (int m = 1; m < 64; m <<= 1) { s1 += __shfl_xor(s1, m); s2 += __shfl_xor(s2, m); }
  if (l == 0) { redbuf[w * 2] = s1; redbuf[w * 2 + 1] = s2; }
  __syncthreads();
  if (tid == 0) {
    float a = redbuf[0] + redbuf[2] + redbuf[4] + redbuf[6];
    float c = redbuf[1] + redbuf[3] + redbuf[5] + redbuf[7];
    atomicAdd(&ostats[h * 2], a);
    atomicAdd(&ostats[h * 2 + 1], c);
  }
}

// FC1 v12 + inline W1 row-sums (mt==0 blocks). BN-affine on A is folded into
// fc1epi via: h1 = alpha_m*acc + beta_m*rowsum(W1[n]) + b1[n]  (normA removed).
__global__ __launch_bounds__(256) void k_fc1(const unsigned short* __restrict__ Ap,
    const float* __restrict__ W1, float* __restrict__ h1acc,
    float* __restrict__ w1rs)
{
  __shared__ __align__(16) unsigned short As[2][128 * 64];
  __shared__ __align__(16) unsigned short Bs[128 * 64];
  const int bid = blockIdx.x;
  const int ks = bid & 7;
  const int mt = (bid >> 3) & 3;
  const int nt = bid >> 5;
  const int m0 = mt * 128, n0 = nt * 128;
  const int kc = ks * 2048;
  const int tid = threadIdx.x, w = tid >> 6, l = tid & 63;
  const int lr = l & 15, lg = l >> 4;
  const int wr = w >> 1, wc = w & 1;
  const int bn = tid >> 4, bq = tid & 15;
  f32x4 acc[4][4];
  #pragma unroll
  for (int i = 0; i < 4; ++i) {
    #pragma unroll
    for (int j = 0; j < 4; ++j) acc[i][j] = (f32x4){0.f, 0.f, 0.f, 0.f};
  }
  float rs[8];
  #pragma unroll
  for (int i = 0; i < 8; ++i) rs[i] = 0.f;

#define LOADB(dst, kbase) do { \
  _Pragma("unroll") \
  for (int j_ = 0; j_ < 8; ++j_) { \
    int n_ = j_ * 16 + bn; \
    dst[j_] = (n0 + n_ < 5000) \
      ? *(const float4*)(W1 + (size_t)(n0 + n_) * 16384 + (kbase) + bq * 4) \
      : make_float4(0.f, 0.f, 0.f, 0.f); \
  } } while (0)

#define WRITEB(src) do { \
  _Pragma("unroll") \
  for (int j_ = 0; j_ < 8; ++j_) { \
    int n_ = j_ * 16 + bn; \
    if (mt == 0) rs[j_] += src[j_].x + src[j_].y + src[j_].z + src[j_].w; \
    unsigned int lo_ = cvtpk(src[j_].x, src[j_].y); \
    unsigned int hi_ = cvtpk(src[j_].z, src[j_].w); \
    int off_ = (n_ << 7) + ((bq * 8) ^ ((n_ & 7) << 4)); \
    *(uint2*)((char*)Bs + off_) = make_uint2(lo_, hi_); \
  } } while (0)

#define STAGEA(BUFI, kbase) do { \
  char* Ad_ = (char*)&As[BUFI][0]; \
  _Pragma("unroll") \
  for (int it_ = 0; it_ < 4; ++it_) { \
    int p_ = it_ * 4096 + tid * 16; \
    int row_ = p_ >> 7; \
    int cl_ = (p_ & 127) ^ ((row_ & 7) << 4); \
    gload16(Ap + (size_t)(m0 + row_) * 16384 + (kbase) + (cl_ >> 1), Ad_ + p_); \
  } } while (0)

#define COMPUTE(BUFI) do { \
  const char* Ac_ = (const char*)&As[BUFI][0]; \
  __builtin_amdgcn_s_setprio(1); \
  _Pragma("unroll") \
  for (int kh_ = 0; kh_ < 2; ++kh_) { \
    short8 af_[4], bf_[4]; \
    _Pragma("unroll") \
    for (int fi_ = 0; fi_ < 4; ++fi_) { \
      int r_ = wr * 64 + fi_ * 16 + lr; \
      int off_ = (r_ << 7) + ((kh_ * 64 + lg * 16) ^ ((r_ & 7) << 4)); \
      af_[fi_] = *(const short8*)(Ac_ + off_); \
    } \
    _Pragma("unroll") \
    for (int fn_ = 0; fn_ < 4; ++fn_) { \
      int n_ = wc * 64 + fn_ * 16 + lr; \
      int off_ = (n_ << 7) + ((kh_ * 64 + lg * 16) ^ ((n_ & 7) << 4)); \
      bf_[fn_] = *(const short8*)((const char*)Bs + off_); \
    } \
    _Pragma("unroll") \
    for (int fi_ = 0; fi_ < 4; ++fi_) { \
      _Pragma("unroll") \
      for (int fn_ = 0; fn_ < 4; ++fn_) \
        acc[fi_][fn_] = MFMA16(af_[fi_], bf_[fn_], acc[fi_][fn_]); \
    } \
  } \
  __builtin_amdgcn_s_setprio(0); \
  } while (0)

#define ITER(BUFI, WCUR, T) do { \
  const int ka_ = kc + (((T) + 1 < 32) ? ((T) + 1) : 31) * 64; \
  const int kb_ = kc + (((T) + 2 < 32) ? ((T) + 2) : 31) * 64; \
  STAGEA((BUFI) ^ 1, ka_); \
  WRITEB(WCUR); \
  LOADB(WCUR, kb_); \
  asm volatile("s_waitcnt vmcnt(20) lgkmcnt(0)" ::: "memory"); \
  __builtin_amdgcn_s_barrier(); \
  __builtin_amdgcn_sched_barrier(0); \
  COMPUTE(BUFI); \
  __builtin_amdgcn_s_barrier(); \
  __builtin_amdgcn_sched_barrier(0); \
  } while (0)

  float4 wA[8], wB[8];
  LOADB(wA, kc);
  STAGEA(0, kc);
  LOADB(wB, kc + 64);
  for (int th = 0; th < 16; ++th) {
    ITER(0, wA, th * 2);
    ITER(1, wB, th * 2 + 1);
  }

#undef LOADB
#undef WRITEB
#undef STAGEA
#undef COMPUTE
#undef ITER

  if (mt == 0) {
    // reduce rs across the 16 bq lanes (tid low 4 bits), then 1 atomic/column
    #pragma unroll
    for (int j = 0; j < 8; ++j) {
      float v = rs[j];
      v += __shfl_xor(v, 1); v += __shfl_xor(v, 2);
      v += __shfl_xor(v, 4); v += __shfl_xor(v, 8);
      if (bq == 0) {
        int col = n0 + j * 16 + bn;
        if (col < 5000) atomicAdd(&w1rs[col], v);
      }
    }
  }

  #pragma unroll
  for (int fi = 0; fi < 4; ++fi) {
    #pragma unroll
    for (int fn = 0; fn < 4; ++fn) {
      int col = n0 + wc * 64 + fn * 16 + lr;
      if (col < 5000) {
        int rowb = m0 + wr * 64 + fi * 16 + lg * 4;
        #pragma unroll
        for (int r = 0; r < 4; ++r)
          atomicAdd(&h1acc[(size_t)(rowb + r) * 5000 + col], acc[fi][fn][r]);
      }
    }
  }
}

// epilogue: h1 = leaky(alpha_m*acc + beta_m*w1rs[n] + b1[n]); alpha/beta from ostats
__global__ __launch_bounds__(256) void k_fc1epi(const float* __restrict__ h1acc,
    const float* __restrict__ b1, const float* __restrict__ w1rs,
    const float* __restrict__ ostats, const float* __restrict__ g1,
    const float* __restrict__ be1, unsigned short* __restrict__ h1act)
{
  __shared__ float oss[32];
  if (threadIdx.x < 16) {
    int h = threadIdx.x;
    const float N = 524288.f;
    float mean = ostats[h * 2] / N;
    float var = ostats[h * 2 + 1] / N - mean * mean;
    float alpha = g1[h] * rsqrtf(var + 1e-5f);
    oss[h * 2] = alpha;
    oss[h * 2 + 1] = be1[h] - mean * alpha;
  }
  __syncthreads();
  int i = blockIdx.x * 256 + threadIdx.x;
  if (i >= 512 * 1280) return;
  int m = i / 1280;
  int o4 = (i - m * 1280) * 4;
  float alpha = oss[(m & 15) * 2], beta = oss[(m & 15) * 2 + 1];
  unsigned int lo = 0, hi = 0;
  if (o4 < 5000) {
    float vv[4];
    #pragma unroll
    for (int j = 0; j < 4; ++j) {
      float x = alpha * h1acc[(size_t)m * 5000 + o4 + j] + beta * w1rs[o4 + j] + b1[o4 + j];
      vv[j] = x >= 0.f ? x : 0.01f * x;
    }
    lo = f2b(vv[0]) | ((unsigned int)f2b(vv[1]) << 16);
    hi = f2b(vv[2]) | ((unsigned int)f2b(vv[3]) << 16);
  }
  *(uint2*)(h1act + (size_t)m * 5120 + o4) = make_uint2(lo, hi);
}

// FC2: splitK=16 (5 K-steps of 64 each), grid (16,8)
__global__ __launch_bounds__(256) void k_fc2(const unsigned short* __restrict__ h1act,
    const unsigned short* __restrict__ w2b, float* __restrict__ h2acc)
{
  __shared__ __align__(16) unsigned short As[64 * 64];
  __shared__ __align__(16) unsigned short Bs[64 * 64];
  const int ks = blockIdx.x, mb = blockIdx.y;
  const int m0 = mb * 64;
  const int k0 = ks * 320;
  const int tid = threadIdx.x, w = tid >> 6, l = tid & 63;
  const int lr = l & 15, lg = l >> 4;
  f32x4 acc[4];
  #pragma unroll
  for (int i = 0; i < 4; ++i) acc[i] = (f32x4){0.f, 0.f, 0.f, 0.f};
  for (int st = 0; st < 5; ++st) {
    const int kbase = k0 + st * 64;
    #pragma unroll
    for (int it = 0; it < 2; ++it) {
      int p = it * 4096 + tid * 16;
      int row = p >> 7;
      int colb = (p & 127) ^ ((row & 7) << 4);
      gload16(h1act + (m0 + row) * 5120 + kbase + (colb >> 1), (char*)As + p);
      gload16(w2b + row * 5120 + kbase + (colb >> 1), (char*)Bs + p);
    }
    __syncthreads();
    #pragma unroll
    for (int kh = 0; kh < 2; ++kh) {
      int ar = w * 16 + lr;
      int aoff = (ar << 7) + (((kh * 32 + lg * 8) * 2) ^ ((ar & 7) << 4));
      short8 af = *(const short8*)((char*)As + aoff);
      #pragma unroll
      for (int fn = 0; fn < 4; ++fn) {
        int n = fn * 16 + lr;
        int boff = (n << 7) + (((kh * 32 + lg * 8) * 2) ^ ((n & 7) << 4));
        short8 bf = *(const short8*)((char*)Bs + boff);
        acc[fn] = MFMA16(af, bf, acc[fn]);
      }
    }
    __syncthreads();
  }
  #pragma unroll
  for (int fn = 0; fn < 4; ++fn) {
    int col = fn * 16 + lr;
    int rowb = m0 + w * 16 + lg * 4;
    #pragma unroll
    for (int r = 0; r < 4; ++r)
      atomicAdd(&h2acc[(rowb + r) * 64 + col], acc[fn][r]);
  }
}

__global__ __launch_bounds__(256) void k_final(const float* __restrict__ h2acc,
    const float* __restrict__ b2, float* __restrict__ outp)
{
  int i = blockIdx.x * 256 + threadIdx.x;
  if (i < 32768) {
    float x = h2acc[i] + b2[i & 63];
    outp[i] = 1.f / (1.f + expf(-x));
  }
}

extern "C" void kernel_launch(void* const* d_in, const int* in_sizes, int n_in,
                              void* d_out, int out_size, void* d_ws, size_t ws_size,
                              hipStream_t stream) {
  const float* q   = (const float*)d_in[0];
  const float* kx  = (const float*)d_in[1];
  const float* vx  = (const float*)d_in[2];
  const float* Wq  = (const float*)d_in[3];
  const float* bq  = (const float*)d_in[4];
  const float* Wk  = (const float*)d_in[5];
  const float* bk  = (const float*)d_in[6];
  const float* Wv  = (const float*)d_in[7];
  const float* bv  = (const float*)d_in[8];
  const float* gq  = (const float*)d_in[9];
  const float* gk  = (const float*)d_in[10];
  const float* gv  = (const float*)d_in[11];
  const float* g1  = (const float*)d_in[12];
  const float* beq = (const float*)d_in[13];
  const float* bek = (const float*)d_in[14];
  const float* bev = (const float*)d_in[15];
  const float* be1 = (const float*)d_in[16];
  const float* W1  = (const float*)d_in[17];
  const float* b1  = (const float*)d_in[18];
  const float* W2  = (const float*)d_in[19];
  const float* b2  = (const float*)d_in[20];

  char* ws = (char*)d_ws;
  unsigned short* qwt = (unsigned short*)(ws + OFF_QWT);
  unsigned short* kwt = (unsigned short*)(ws + OFF_KWT);
  unsigned short* vwt = (unsigned short*)(ws + OFF_VWT);
  float* proj   = (float*)(ws + OFF_O);
  unsigned short* Abf = (unsigned short*)(ws + OFF_A);
  float* h1acc  = (float*)(ws + OFF_H1ACC);
  unsigned short* h1act = (unsigned short*)(ws + OFF_H1ACT);
  unsigned short* w2b   = (unsigned short*)(ws + OFF_W2B);
  float* h2acc  = (float*)(ws + OFF_H2ACC);
  float* rows   = (float*)(ws + OFF_ROWS);
  float* ostats = (float*)(ws + OFF_OSTAT);
  float* w1rs   = (float*)(ws + OFF_W1RS);

  k_prep<<<2048, 256, 0, stream>>>(h1acc, 2560000, h2acc, 34944, w1rs, 5056, W2, w2b);
  k_proj3<<<dim3(8, 32, 3), 256, 0, stream>>>(q, kx, vx, Wq, Wk, Wv, bq, bk, bv, proj, rows);
  k_winnorm<<<dim3(16, 32, 3), 256, 0, stream>>>(proj, rows, gq, gk, gv, beq, bek, bev,
                                                 qwt, kwt, vwt);
  k_attn<<<dim3(16, 32), 256, 0, stream>>>(qwt, kwt, vwt, Abf, ostats);
  k_fc1<<<1280, 256, 0, stream>>>(Abf, W1, h1acc, w1rs);
  k_fc1epi<<<2560, 256, 0, stream>>>(h1acc, b1, w1rs, ostats, g1, be1, h1act);
  k_fc2<<<dim3(16, 8), 256, 0, stream>>>(h1act, w2b, h2acc);
  k_final<<<128, 256, 0, stream>>>(h2acc, b2, (float*)d_out);
}

// Round 16
// 492.248 us; speedup vs baseline: 1.1869x; 1.1869x over previous
//
#include <hip/hip_runtime.h>
#include <cstdint>
#include <cstddef>

typedef __attribute__((ext_vector_type(8))) short short8;
typedef __attribute__((ext_vector_type(4))) float f32x4;

#define MFMA16(a,b,c) __builtin_amdgcn_mfma_f32_16x16x32_bf16((a),(b),(c),0,0,0)

// ---------------- ws layout (bytes) ----------------
#define OFF_QWT   0ull
#define OFF_KWT   16777216ull
#define OFF_VWT   33554432ull
#define OFF_O     50331648ull
#define OFF_A     83886080ull
#define OFF_H1ACC 100663296ull
#define OFF_H1ACT 110903296ull
#define OFF_W2B   116146176ull
#define OFF_H2ACC 116801536ull
#define OFF_ROWS  116932608ull
#define OFF_OSTAT 116940800ull

__device__ __forceinline__ unsigned short f2b(float x) {
  union { float f; unsigned int u; } v; v.f = x;
  unsigned int r = v.u + 0x7fffu + ((v.u >> 16) & 1u);
  return (unsigned short)(r >> 16);
}

__device__ __forceinline__ float b2f(unsigned int u16) {
  union { unsigned int u; float f; } v; v.u = u16 << 16;
  return v.f;
}

__device__ __forceinline__ unsigned int cvtpk(float a, float b) {
  unsigned int r;
  asm("v_cvt_pk_bf16_f32 %0, %1, %2" : "=v"(r) : "v"(a), "v"(b));
  return r;
}

__device__ __forceinline__ void gload16(const void* g, void* l) {
  __builtin_amdgcn_global_load_lds((const __attribute__((address_space(1))) unsigned int*)g,
                                   (__attribute__((address_space(3))) unsigned int*)l,
                                   16, 0, 0);
}

// zero h1acc/h2acc + convert W2 -> bf16 padded, one launch
__global__ __launch_bounds__(256) void k_prep(float* __restrict__ p1, int n1,
                                              float* __restrict__ p2, int n2,
                                              const float* __restrict__ W2,
                                              unsigned short* __restrict__ w2b) {
  int i = blockIdx.x * 256 + threadIdx.x;
  int nz = n1 + n2;
  int total = nz + 64 * 1280;
  for (; i < total; i += gridDim.x * 256) {
    if (i < n1) p1[i] = 0.f;
    else if (i < nz) p2[i - n1] = 0.f;
    else {
      int j = i - nz;
      int n = j / 1280;
      int o4 = (j - n * 1280) * 4;
      unsigned int lo = 0, hi = 0;
      if (o4 < 5000) {
        lo = f2b(W2[n * 5000 + o4]) | ((unsigned int)f2b(W2[n * 5000 + o4 + 1]) << 16);
        hi = f2b(W2[n * 5000 + o4 + 2]) | ((unsigned int)f2b(W2[n * 5000 + o4 + 3]) << 16);
      }
      *(uint2*)(w2b + (size_t)n * 5120 + o4) = make_uint2(lo, hi);
    }
  }
}

__global__ __launch_bounds__(256) void k_proj3(const float* __restrict__ qx,
    const float* __restrict__ kx, const float* __restrict__ vx,
    const float* __restrict__ Wq, const float* __restrict__ Wk, const float* __restrict__ Wv,
    const float* __restrict__ bqv, const float* __restrict__ bkv, const float* __restrict__ bvv,
    float* __restrict__ proj, float* __restrict__ rowsb)
{
  __shared__ float xs[124][32];
  __shared__ float Wsh[124 * 124];
  const int sc = blockIdx.x, b = blockIdx.y, t = blockIdx.z;
  const float* x = (t == 0) ? qx : (t == 1) ? kx : vx;
  const float* W = (t == 0) ? Wq : (t == 1) ? Wk : Wv;
  const float* bias = (t == 0) ? bqv : (t == 1) ? bkv : bvv;
  float* out = proj + (size_t)t * 1048576;
  float* rowstat = rowsb + t * 248;
  const int s0 = sc * 32;
  const int tid = threadIdx.x;
  const float* xb = x + (size_t)b * 124 * 256;
  for (int e = tid; e < 15376; e += 256) Wsh[e] = W[e];
  for (int e = tid; e < 3968; e += 256) {
    int f = e >> 5, s = e & 31;
    xs[f][s] = xb[f * 256 + s0 + s];
  }
  __syncthreads();
  float* ob = out + (size_t)b * 124 * 256;
  for (int base = 0; base < 3968; base += 256) {
    int e = base + tid;
    bool valid = e < 3968;
    int g = valid ? (e >> 5) : 0;
    int s = e & 31;
    float acc = 0.f;
    if (valid) {
      acc = bias[g];
      const float* wr = Wsh + g * 124;
      #pragma unroll 4
      for (int f = 0; f < 124; ++f) acc += wr[f] * xs[f][s];
      ob[g * 256 + s0 + s] = acc;
    }
    float v1 = valid ? acc : 0.f;
    float v2 = v1 * v1;
    #pragma unroll
    for (int m = 1; m < 32; m <<= 1) { v1 += __shfl_xor(v1, m); v2 += __shfl_xor(v2, m); }
    if (valid && (tid & 31) == 0) {
      atomicAdd(&rowstat[g * 2], v1);
      atomicAdd(&rowstat[g * 2 + 1], v2);
    }
  }
}

// winnorm + inline headstats: each block derives its (t,h) scale/shift from rows.
__global__ __launch_bounds__(256) void k_winnorm(const float* __restrict__ proj,
    const float* __restrict__ rows,
    const float* __restrict__ gq, const float* __restrict__ gk, const float* __restrict__ gv,
    const float* __restrict__ beq, const float* __restrict__ bek, const float* __restrict__ bev,
    unsigned short* __restrict__ outq, unsigned short* __restrict__ outk,
    unsigned short* __restrict__ outv)
{
  __shared__ float T[64][65];
  __shared__ float ssh[2];
  const int h = blockIdx.x, b = blockIdx.y, t = blockIdx.z;
  const int tid = threadIdx.x;
  if (tid == 0) {
    const float* rp = rows + t * 248;
    float s = 0.f, q = 0.f;
    for (int j = 0; j < 64; ++j) {
      s += rp[(h * 4 + j) * 2];
      q += rp[(h * 4 + j) * 2 + 1];
    }
    const float N = 524288.f;
    float mean = s / N;
    float var = q / N - mean * mean;
    float gamma = (t == 0 ? gq[h] : (t == 1 ? gk[h] : gv[h]));
    float beta  = (t == 0 ? beq[h] : (t == 1 ? bek[h] : bev[h]));
    float scale = gamma * rsqrtf(var + 1e-5f);
    ssh[0] = scale;
    ssh[1] = beta - mean * scale;
  }
  __syncthreads();
  const float scale = ssh[0], shift = ssh[1];
  const float* in = proj + (size_t)t * 1048576 + (size_t)(b * 124 + h * 4) * 256;
  const size_t obase = (size_t)(b * 16 + h) * 16384;
  if (t < 2) {
    unsigned short* out = (t == 0 ? outq : outk) + obase;
    for (int sc = 0; sc < 4; ++sc) {
      const int s0 = sc * 64;
      for (int e = tid; e < 1024; e += 256) {
        int g = e >> 4, qq = e & 15;
        float4 val = *(const float4*)(in + g * 256 + s0 + qq * 4);
        T[g][qq * 4 + 0] = val.x * scale + shift;
        T[g][qq * 4 + 1] = val.y * scale + shift;
        T[g][qq * 4 + 2] = val.z * scale + shift;
        T[g][qq * 4 + 3] = val.w * scale + shift;
      }
      __syncthreads();
      for (int e = tid; e < 512; e += 256) {
        int sl = e >> 3, j0 = (e & 7) * 8;
        unsigned int pk[4];
        #pragma unroll
        for (int jj = 0; jj < 4; ++jj) {
          unsigned int a0 = f2b(T[j0 + jj * 2][sl]);
          unsigned int a1 = f2b(T[j0 + jj * 2 + 1][sl]);
          pk[jj] = a0 | (a1 << 16);
        }
        *(uint4*)(out + (s0 + sl) * 64 + j0) = make_uint4(pk[0], pk[1], pk[2], pk[3]);
      }
      __syncthreads();
    }
  } else {
    unsigned short* out = outv + obase;
    for (int e = tid * 4; e < 16384; e += 1024) {
      float4 val = *(const float4*)(in + e);
      unsigned int lo = f2b(val.x * scale + shift) | ((unsigned int)f2b(val.y * scale + shift) << 16);
      unsigned int hi = f2b(val.z * scale + shift) | ((unsigned int)f2b(val.w * scale + shift) << 16);
      *(uint2*)(out + e) = make_uint2(lo, hi);
    }
  }
}

__global__ __launch_bounds__(256) void k_attn(const unsigned short* __restrict__ qwt,
    const unsigned short* __restrict__ kwt, const unsigned short* __restrict__ vwt,
    unsigned short* __restrict__ ob, float* __restrict__ ostats)
{
  __shared__ __align__(16) unsigned short P[4][16 * 256];
  __shared__ float redbuf[8];
  const int h = blockIdx.x, b = blockIdx.y;
  const int bh = b * 16 + h;
  const unsigned short* Q = qwt + (size_t)bh * 16384;
  const unsigned short* K = kwt + (size_t)bh * 16384;
  const unsigned short* V = vwt + (size_t)bh * 16384;
  const int tid = threadIdx.x, w = tid >> 6, l = tid & 63;
  const int lr = l & 15, lg = l >> 4;
  char* Pw = (char*)&P[w][0];
  float s1 = 0.f, s2 = 0.f;
  for (int ch = 0; ch < 4; ++ch) {
    const int i0 = w * 64 + ch * 16;
    short8 qf0 = *(const short8*)(Q + (i0 + lr) * 64 + lg * 8);
    short8 qf1 = *(const short8*)(Q + (i0 + lr) * 64 + 32 + lg * 8);
    f32x4 S[16];
    #pragma unroll
    for (int jt = 0; jt < 16; ++jt) {
      const unsigned short* Kr = K + (jt * 16 + lr) * 64 + lg * 8;
      short8 kf0 = *(const short8*)(Kr);
      short8 kf1 = *(const short8*)(Kr + 32);
      f32x4 a = {0.f, 0.f, 0.f, 0.f};
      a = MFMA16(qf0, kf0, a);
      a = MFMA16(qf1, kf1, a);
      S[jt] = a;
    }
    float mx[4], sm[4], rinv[4];
    #pragma unroll
    for (int r = 0; r < 4; ++r) {
      float m = S[0][r];
      #pragma unroll
      for (int jt = 1; jt < 16; ++jt) m = fmaxf(m, S[jt][r]);
      m = fmaxf(m, __shfl_xor(m, 1));
      m = fmaxf(m, __shfl_xor(m, 2));
      m = fmaxf(m, __shfl_xor(m, 4));
      m = fmaxf(m, __shfl_xor(m, 8));
      mx[r] = m; sm[r] = 0.f;
    }
    #pragma unroll
    for (int jt = 0; jt < 16; ++jt) {
      #pragma unroll
      for (int r = 0; r < 4; ++r) {
        float p = exp2f((S[jt][r] - mx[r]) * 0.18033688011112042f);
        sm[r] += p;
        S[jt][r] = p;
      }
    }
    #pragma unroll
    for (int r = 0; r < 4; ++r) {
      float s = sm[r];
      s += __shfl_xor(s, 1); s += __shfl_xor(s, 2);
      s += __shfl_xor(s, 4); s += __shfl_xor(s, 8);
      rinv[r] = 1.0f / s;
    }
    #pragma unroll
    for (int jt = 0; jt < 16; ++jt) {
      #pragma unroll
      for (int r = 0; r < 4; ++r) {
        int rr = lg * 4 + r;
        int c = jt * 16 + lr;
        int off = rr * 512 + ((c * 2) ^ ((rr & 7) << 4));
        *(unsigned short*)(Pw + off) = f2b(S[jt][r]);
      }
    }
    asm volatile("s_waitcnt lgkmcnt(0)" ::: "memory");
    f32x4 O[4];
    #pragma unroll
    for (int nt = 0; nt < 4; ++nt) O[nt] = (f32x4){0.f, 0.f, 0.f, 0.f};
    #pragma unroll
    for (int js = 0; js < 8; ++js) {
      int off = lr * 512 + (((js * 32 + lg * 8) * 2) ^ ((lr & 7) << 4));
      short8 pf = *(const short8*)(Pw + off);
      #pragma unroll
      for (int nt = 0; nt < 4; ++nt) {
        short8 vf = *(const short8*)(V + (nt * 16 + lr) * 256 + js * 32 + lg * 8);
        O[nt] = MFMA16(pf, vf, O[nt]);
      }
    }
    unsigned short* orow = ob + (size_t)bh * 16384 + (size_t)i0 * 64;
    #pragma unroll
    for (int nt = 0; nt < 4; ++nt) {
      #pragma unroll
      for (int r = 0; r < 4; ++r) {
        float val = O[nt][r] * rinv[r];
        orow[(lg * 4 + r) * 64 + nt * 16 + lr] = f2b(val);
        s1 += val; s2 += val * val;
      }
    }
  }
  #pragma unroll
  for (int m = 1; m < 64; m <<= 1) { s1 += __shfl_xor(s1, m); s2 += __shfl_xor(s2, m); }
  if (l == 0) { redbuf[w * 2] = s1; redbuf[w * 2 + 1] = s2; }
  __syncthreads();
  if (tid == 0) {
    float a = redbuf[0] + redbuf[2] + redbuf[4] + redbuf[6];
    float c = redbuf[1] + redbuf[3] + redbuf[5] + redbuf[7];
    atomicAdd(&ostats[h * 2], a);
    atomicAdd(&ostats[h * 2 + 1], c);
  }
}

// in-place affine on bf16 A; alpha/beta computed inline from ostats (k_oscale folded in)
__global__ __launch_bounds__(256) void k_normA(unsigned short* __restrict__ A,
    const float* __restrict__ ostats,
    const float* __restrict__ g1, const float* __restrict__ be1)
{
  __shared__ float oss[32];
  if (threadIdx.x < 16) {
    int h = threadIdx.x;
    const float N = 524288.f;
    float mean = ostats[h * 2] / N;
    float var = ostats[h * 2 + 1] / N - mean * mean;
    float alpha = g1[h] * rsqrtf(var + 1e-5f);
    oss[h * 2] = alpha;
    oss[h * 2 + 1] = be1[h] - mean * alpha;
  }
  __syncthreads();
  int idx = blockIdx.x * 256 + threadIdx.x;
  for (int i = idx; i < 1048576; i += 1024 * 256) {
    int m = i >> 11;
    int hh = m & 15;
    float alpha = oss[hh * 2], beta = oss[hh * 2 + 1];
    uint4 v = ((const uint4*)A)[i];
    unsigned int o0, o1, o2, o3;
    {
      float a = b2f(v.x & 0xffffu) * alpha + beta;
      float b = b2f(v.x >> 16) * alpha + beta;
      o0 = (unsigned int)f2b(a) | ((unsigned int)f2b(b) << 16);
    }
    {
      float a = b2f(v.y & 0xffffu) * alpha + beta;
      float b = b2f(v.y >> 16) * alpha + beta;
      o1 = (unsigned int)f2b(a) | ((unsigned int)f2b(b) << 16);
    }
    {
      float a = b2f(v.z & 0xffffu) * alpha + beta;
      float b = b2f(v.z >> 16) * alpha + beta;
      o2 = (unsigned int)f2b(a) | ((unsigned int)f2b(b) << 16);
    }
    {
      float a = b2f(v.w & 0xffffu) * alpha + beta;
      float b = b2f(v.w >> 16) * alpha + beta;
      o3 = (unsigned int)f2b(a) | ((unsigned int)f2b(b) << 16);
    }
    ((uint4*)A)[i] = make_uint4(o0, o1, o2, o3);
  }
}

// FC1 v12 (best known: 216us): depth-2 counted-vmcnt pipeline, BM=128 BN=128
// BK=64 splitK=8, grid 1280, XCD-coherent bid (ks=bid&7). vmcnt(20) ledger:
// after LOADB(t+2): B(t+1)[8]+A(t+1)[4]+B(t+2)[8]=20 outstanding, drains A(t).
__global__ __launch_bounds__(256) void k_fc1(const unsigned short* __restrict__ Ap,
    const float* __restrict__ W1, float* __restrict__ h1acc)
{
  __shared__ __align__(16) unsigned short As[2][128 * 64];
  __shared__ __align__(16) unsigned short Bs[128 * 64];
  const int bid = blockIdx.x;
  const int ks = bid & 7;
  const int mt = (bid >> 3) & 3;
  const int nt = bid >> 5;
  const int m0 = mt * 128, n0 = nt * 128;
  const int kc = ks * 2048;
  const int tid = threadIdx.x, w = tid >> 6, l = tid & 63;
  const int lr = l & 15, lg = l >> 4;
  const int wr = w >> 1, wc = w & 1;
  const int bn = tid >> 4, bq = tid & 15;
  f32x4 acc[4][4];
  #pragma unroll
  for (int i = 0; i < 4; ++i) {
    #pragma unroll
    for (int j = 0; j < 4; ++j) acc[i][j] = (f32x4){0.f, 0.f, 0.f, 0.f};
  }

#define LOADB(dst, kbase) do { \
  _Pragma("unroll") \
  for (int j_ = 0; j_ < 8; ++j_) { \
    int n_ = j_ * 16 + bn; \
    dst[j_] = (n0 + n_ < 5000) \
      ? *(const float4*)(W1 + (size_t)(n0 + n_) * 16384 + (kbase) + bq * 4) \
      : make_float4(0.f, 0.f, 0.f, 0.f); \
  } } while (0)

#define WRITEB(src) do { \
  _Pragma("unroll") \
  for (int j_ = 0; j_ < 8; ++j_) { \
    int n_ = j_ * 16 + bn; \
    unsigned int lo_ = cvtpk(src[j_].x, src[j_].y); \
    unsigned int hi_ = cvtpk(src[j_].z, src[j_].w); \
    int off_ = (n_ << 7) + ((bq * 8) ^ ((n_ & 7) << 4)); \
    *(uint2*)((char*)Bs + off_) = make_uint2(lo_, hi_); \
  } } while (0)

#define STAGEA(BUFI, kbase) do { \
  char* Ad_ = (char*)&As[BUFI][0]; \
  _Pragma("unroll") \
  for (int it_ = 0; it_ < 4; ++it_) { \
    int p_ = it_ * 4096 + tid * 16; \
    int row_ = p_ >> 7; \
    int cl_ = (p_ & 127) ^ ((row_ & 7) << 4); \
    gload16(Ap + (size_t)(m0 + row_) * 16384 + (kbase) + (cl_ >> 1), Ad_ + p_); \
  } } while (0)

#define COMPUTE(BUFI) do { \
  const char* Ac_ = (const char*)&As[BUFI][0]; \
  __builtin_amdgcn_s_setprio(1); \
  _Pragma("unroll") \
  for (int kh_ = 0; kh_ < 2; ++kh_) { \
    short8 af_[4], bf_[4]; \
    _Pragma("unroll") \
    for (int fi_ = 0; fi_ < 4; ++fi_) { \
      int r_ = wr * 64 + fi_ * 16 + lr; \
      int off_ = (r_ << 7) + ((kh_ * 64 + lg * 16) ^ ((r_ & 7) << 4)); \
      af_[fi_] = *(const short8*)(Ac_ + off_); \
    } \
    _Pragma("unroll") \
    for (int fn_ = 0; fn_ < 4; ++fn_) { \
      int n_ = wc * 64 + fn_ * 16 + lr; \
      int off_ = (n_ << 7) + ((kh_ * 64 + lg * 16) ^ ((n_ & 7) << 4)); \
      bf_[fn_] = *(const short8*)((const char*)Bs + off_); \
    } \
    _Pragma("unroll") \
    for (int fi_ = 0; fi_ < 4; ++fi_) { \
      _Pragma("unroll") \
      for (int fn_ = 0; fn_ < 4; ++fn_) \
        acc[fi_][fn_] = MFMA16(af_[fi_], bf_[fn_], acc[fi_][fn_]); \
    } \
  } \
  __builtin_amdgcn_s_setprio(0); \
  } while (0)

#define ITER(BUFI, WCUR, T) do { \
  const int ka_ = kc + (((T) + 1 < 32) ? ((T) + 1) : 31) * 64; \
  const int kb_ = kc + (((T) + 2 < 32) ? ((T) + 2) : 31) * 64; \
  STAGEA((BUFI) ^ 1, ka_); \
  WRITEB(WCUR); \
  LOADB(WCUR, kb_); \
  asm volatile("s_waitcnt vmcnt(20) lgkmcnt(0)" ::: "memory"); \
  __builtin_amdgcn_s_barrier(); \
  __builtin_amdgcn_sched_barrier(0); \
  COMPUTE(BUFI); \
  __builtin_amdgcn_s_barrier(); \
  __builtin_amdgcn_sched_barrier(0); \
  } while (0)

  float4 wA[8], wB[8];
  // prologue: group order B(0)[8], A(0)[4], B(1)[8] (mirrors steady state)
  LOADB(wA, kc);
  STAGEA(0, kc);
  LOADB(wB, kc + 64);
  for (int th = 0; th < 16; ++th) {
    ITER(0, wA, th * 2);
    ITER(1, wB, th * 2 + 1);
  }

#undef LOADB
#undef WRITEB
#undef STAGEA
#undef COMPUTE
#undef ITER

  #pragma unroll
  for (int fi = 0; fi < 4; ++fi) {
    #pragma unroll
    for (int fn = 0; fn < 4; ++fn) {
      int col = n0 + wc * 64 + fn * 16 + lr;
      if (col < 5000) {
        int rowb = m0 + wr * 64 + fi * 16 + lg * 4;
        #pragma unroll
        for (int r = 0; r < 4; ++r)
          atomicAdd(&h1acc[(size_t)(rowb + r) * 5000 + col], acc[fi][fn][r]);
      }
    }
  }
}

__global__ __launch_bounds__(256) void k_fc1epi(const float* __restrict__ h1acc,
    const float* __restrict__ b1, unsigned short* __restrict__ h1act)
{
  int i = blockIdx.x * 256 + threadIdx.x;
  if (i >= 512 * 1280) return;
  int m = i / 1280;
  int o4 = (i - m * 1280) * 4;
  unsigned int lo = 0, hi = 0;
  if (o4 < 5000) {
    float vv[4];
    #pragma unroll
    for (int j = 0; j < 4; ++j) {
      float x = h1acc[(size_t)m * 5000 + o4 + j] + b1[o4 + j];
      vv[j] = x >= 0.f ? x : 0.01f * x;
    }
    lo = f2b(vv[0]) | ((unsigned int)f2b(vv[1]) << 16);
    hi = f2b(vv[2]) | ((unsigned int)f2b(vv[3]) << 16);
  }
  *(uint2*)(h1act + (size_t)m * 5120 + o4) = make_uint2(lo, hi);
}

// FC2: splitK=16 (5 K-steps of 64 each), grid (16,8)
__global__ __launch_bounds__(256) void k_fc2(const unsigned short* __restrict__ h1act,
    const unsigned short* __restrict__ w2b, float* __restrict__ h2acc)
{
  __shared__ __align__(16) unsigned short As[64 * 64];
  __shared__ __align__(16) unsigned short Bs[64 * 64];
  const int ks = blockIdx.x, mb = blockIdx.y;
  const int m0 = mb * 64;
  const int k0 = ks * 320;
  const int tid = threadIdx.x, w = tid >> 6, l = tid & 63;
  const int lr = l & 15, lg = l >> 4;
  f32x4 acc[4];
  #pragma unroll
  for (int i = 0; i < 4; ++i) acc[i] = (f32x4){0.f, 0.f, 0.f, 0.f};
  for (int st = 0; st < 5; ++st) {
    const int kbase = k0 + st * 64;
    #pragma unroll
    for (int it = 0; it < 2; ++it) {
      int p = it * 4096 + tid * 16;
      int row = p >> 7;
      int colb = (p & 127) ^ ((row & 7) << 4);
      gload16(h1act + (m0 + row) * 5120 + kbase + (colb >> 1), (char*)As + p);
      gload16(w2b + row * 5120 + kbase + (colb >> 1), (char*)Bs + p);
    }
    __syncthreads();
    #pragma unroll
    for (int kh = 0; kh < 2; ++kh) {
      int ar = w * 16 + lr;
      int aoff = (ar << 7) + (((kh * 32 + lg * 8) * 2) ^ ((ar & 7) << 4));
      short8 af = *(const short8*)((char*)As + aoff);
      #pragma unroll
      for (int fn = 0; fn < 4; ++fn) {
        int n = fn * 16 + lr;
        int boff = (n << 7) + (((kh * 32 + lg * 8) * 2) ^ ((n & 7) << 4));
        short8 bf = *(const short8*)((char*)Bs + boff);
        acc[fn] = MFMA16(af, bf, acc[fn]);
      }
    }
    __syncthreads();
  }
  #pragma unroll
  for (int fn = 0; fn < 4; ++fn) {
    int col = fn * 16 + lr;
    int rowb = m0 + w * 16 + lg * 4;
    #pragma unroll
    for (int r = 0; r < 4; ++r)
      atomicAdd(&h2acc[(rowb + r) * 64 + col], acc[fn][r]);
  }
}

__global__ __launch_bounds__(256) void k_final(const float* __restrict__ h2acc,
    const float* __restrict__ b2, float* __restrict__ outp)
{
  int i = blockIdx.x * 256 + threadIdx.x;
  if (i < 32768) {
    float x = h2acc[i] + b2[i & 63];
    outp[i] = 1.f / (1.f + expf(-x));
  }
}

extern "C" void kernel_launch(void* const* d_in, const int* in_sizes, int n_in,
                              void* d_out, int out_size, void* d_ws, size_t ws_size,
                              hipStream_t stream) {
  const float* q   = (const float*)d_in[0];
  const float* kx  = (const float*)d_in[1];
  const float* vx  = (const float*)d_in[2];
  const float* Wq  = (const float*)d_in[3];
  const float* bq  = (const float*)d_in[4];
  const float* Wk  = (const float*)d_in[5];
  const float* bk  = (const float*)d_in[6];
  const float* Wv  = (const float*)d_in[7];
  const float* bv  = (const float*)d_in[8];
  const float* gq  = (const float*)d_in[9];
  const float* gk  = (const float*)d_in[10];
  const float* gv  = (const float*)d_in[11];
  const float* g1  = (const float*)d_in[12];
  const float* beq = (const float*)d_in[13];
  const float* bek = (const float*)d_in[14];
  const float* bev = (const float*)d_in[15];
  const float* be1 = (const float*)d_in[16];
  const float* W1  = (const float*)d_in[17];
  const float* b1  = (const float*)d_in[18];
  const float* W2  = (const float*)d_in[19];
  const float* b2  = (const float*)d_in[20];

  char* ws = (char*)d_ws;
  unsigned short* qwt = (unsigned short*)(ws + OFF_QWT);
  unsigned short* kwt = (unsigned short*)(ws + OFF_KWT);
  unsigned short* vwt = (unsigned short*)(ws + OFF_VWT);
  float* proj   = (float*)(ws + OFF_O);
  unsigned short* Abf = (unsigned short*)(ws + OFF_A);
  float* h1acc  = (float*)(ws + OFF_H1ACC);
  unsigned short* h1act = (unsigned short*)(ws + OFF_H1ACT);
  unsigned short* w2b   = (unsigned short*)(ws + OFF_W2B);
  float* h2acc  = (float*)(ws + OFF_H2ACC);
  float* rows   = (float*)(ws + OFF_ROWS);
  float* ostats = (float*)(ws + OFF_OSTAT);

  k_prep<<<2048, 256, 0, stream>>>(h1acc, 2560000, h2acc, 34944, W2, w2b);
  k_proj3<<<dim3(8, 32, 3), 256, 0, stream>>>(q, kx, vx, Wq, Wk, Wv, bq, bk, bv, proj, rows);
  k_winnorm<<<dim3(16, 32, 3), 256, 0, stream>>>(proj, rows, gq, gk, gv, beq, bek, bev,
                                                 qwt, kwt, vwt);
  k_attn<<<dim3(16, 32), 256, 0, stream>>>(qwt, kwt, vwt, Abf, ostats);
  k_normA<<<1024, 256, 0, stream>>>(Abf, ostats, g1, be1);
  k_fc1<<<1280, 256, 0, stream>>>(Abf, W1, h1acc);
  k_fc1epi<<<2560, 256, 0, stream>>>(h1acc, b1, h1act);
  k_fc2<<<dim3(16, 8), 256, 0, stream>>>(h1act, w2b, h2acc);
  k_final<<<128, 256, 0, stream>>>(h2acc, b2, (float*)d_out);
}

// Round 17
// 388.346 us; speedup vs baseline: 1.5045x; 1.2676x over previous
//
#include <hip/hip_runtime.h>
#include <cstdint>
#include <cstddef>

typedef __attribute__((ext_vector_type(8))) short short8;
typedef __attribute__((ext_vector_type(4))) float f32x4;

#define MFMA16(a,b,c) __builtin_amdgcn_mfma_f32_16x16x32_bf16((a),(b),(c),0,0,0)

// ---------------- ws layout (bytes) ----------------
#define OFF_QWT   0ull
#define OFF_KWT   16777216ull
#define OFF_VWT   33554432ull
#define OFF_O     50331648ull
#define OFF_A     83886080ull
#define OFF_H1ACC 100663296ull
#define OFF_H1ACT 110903296ull
#define OFF_W2B   116146176ull
#define OFF_H2ACC 116801536ull
#define OFF_ROWS  116932608ull
#define OFF_OSTAT 116940800ull

__device__ __forceinline__ unsigned short f2b(float x) {
  union { float f; unsigned int u; } v; v.f = x;
  unsigned int r = v.u + 0x7fffu + ((v.u >> 16) & 1u);
  return (unsigned short)(r >> 16);
}

__device__ __forceinline__ float b2f(unsigned int u16) {
  union { unsigned int u; float f; } v; v.u = u16 << 16;
  return v.f;
}

__device__ __forceinline__ unsigned int cvtpk(float a, float b) {
  unsigned int r;
  asm("v_cvt_pk_bf16_f32 %0, %1, %2" : "=v"(r) : "v"(a), "v"(b));
  return r;
}

__device__ __forceinline__ void gload16(const void* g, void* l) {
  __builtin_amdgcn_global_load_lds((const __attribute__((address_space(1))) unsigned int*)g,
                                   (__attribute__((address_space(3))) unsigned int*)l,
                                   16, 0, 0);
}

// zero h1acc/h2acc + convert W2 -> bf16 padded, one launch
__global__ __launch_bounds__(256) void k_prep(float* __restrict__ p1, int n1,
                                              float* __restrict__ p2, int n2,
                                              const float* __restrict__ W2,
                                              unsigned short* __restrict__ w2b) {
  int i = blockIdx.x * 256 + threadIdx.x;
  int nz = n1 + n2;
  int total = nz + 64 * 1280;
  for (; i < total; i += gridDim.x * 256) {
    if (i < n1) p1[i] = 0.f;
    else if (i < nz) p2[i - n1] = 0.f;
    else {
      int j = i - nz;
      int n = j / 1280;
      int o4 = (j - n * 1280) * 4;
      unsigned int lo = 0, hi = 0;
      if (o4 < 5000) {
        lo = f2b(W2[n * 5000 + o4]) | ((unsigned int)f2b(W2[n * 5000 + o4 + 1]) << 16);
        hi = f2b(W2[n * 5000 + o4 + 2]) | ((unsigned int)f2b(W2[n * 5000 + o4 + 3]) << 16);
      }
      *(uint2*)(w2b + (size_t)n * 5120 + o4) = make_uint2(lo, hi);
    }
  }
}

// proj v2: 4 outputs/thread (float4 over s). Per f: 1 broadcast W read +
// 1 ds_read_b128 xs + 4 FMA -> ~2x issue efficiency vs scalar version.
// grid (2 sc, 32 b, 3 t); xs f32 [124][128] + Wsh = 125KB LDS.
__global__ __launch_bounds__(256) void k_proj3(const float* __restrict__ qx,
    const float* __restrict__ kx, const float* __restrict__ vx,
    const float* __restrict__ Wq, const float* __restrict__ Wk, const float* __restrict__ Wv,
    const float* __restrict__ bqv, const float* __restrict__ bkv, const float* __restrict__ bvv,
    float* __restrict__ proj, float* __restrict__ rowsb)
{
  __shared__ float xs[124][128];
  __shared__ float Wsh[124 * 124];
  const int sc = blockIdx.x, b = blockIdx.y, t = blockIdx.z;
  const float* x = (t == 0) ? qx : (t == 1) ? kx : vx;
  const float* W = (t == 0) ? Wq : (t == 1) ? Wk : Wv;
  const float* bias = (t == 0) ? bqv : (t == 1) ? bkv : bvv;
  float* out = proj + (size_t)t * 1048576;
  float* rowstat = rowsb + t * 248;
  const int s0 = sc * 128;
  const int tid = threadIdx.x;
  const float* xb = x + (size_t)b * 124 * 256;
  for (int e = tid; e < 15376; e += 256) Wsh[e] = W[e];
  for (int e = tid; e < 15872; e += 256) {
    int f = e >> 7, s = e & 127;
    xs[f][s] = xb[f * 256 + s0 + s];
  }
  __syncthreads();
  float* ob = out + (size_t)b * 124 * 256;
  // work items: 124 g x 32 quads = 3968; 15.5 iterations of 256
  for (int base = 0; base < 3968; base += 256) {
    int e = base + tid;
    bool valid = e < 3968;
    int g = valid ? (e >> 5) : 0;
    int qd = e & 31;                 // float4 index within the 128-s slab
    float4 acc = make_float4(0.f, 0.f, 0.f, 0.f);
    if (valid) {
      const float* wr = Wsh + g * 124;
      #pragma unroll 4
      for (int f = 0; f < 124; ++f) {
        float wv = wr[f];
        float4 xv = *(const float4*)(&xs[f][qd * 4]);
        acc.x += wv * xv.x;
        acc.y += wv * xv.y;
        acc.z += wv * xv.z;
        acc.w += wv * xv.w;
      }
      float bg = bias[g];
      acc.x += bg; acc.y += bg; acc.z += bg; acc.w += bg;
      *(float4*)(ob + g * 256 + s0 + qd * 4) = acc;
    }
    float v1 = valid ? (acc.x + acc.y + acc.z + acc.w) : 0.f;
    float v2 = valid ? (acc.x * acc.x + acc.y * acc.y + acc.z * acc.z + acc.w * acc.w) : 0.f;
    #pragma unroll
    for (int m = 1; m < 32; m <<= 1) { v1 += __shfl_xor(v1, m); v2 += __shfl_xor(v2, m); }
    if (valid && (tid & 31) == 0) {
      atomicAdd(&rowstat[g * 2], v1);
      atomicAdd(&rowstat[g * 2 + 1], v2);
    }
  }
}

// winnorm + inline headstats: each block derives its (t,h) scale/shift from rows.
__global__ __launch_bounds__(256) void k_winnorm(const float* __restrict__ proj,
    const float* __restrict__ rows,
    const float* __restrict__ gq, const float* __restrict__ gk, const float* __restrict__ gv,
    const float* __restrict__ beq, const float* __restrict__ bek, const float* __restrict__ bev,
    unsigned short* __restrict__ outq, unsigned short* __restrict__ outk,
    unsigned short* __restrict__ outv)
{
  __shared__ float T[64][65];
  __shared__ float ssh[2];
  const int h = blockIdx.x, b = blockIdx.y, t = blockIdx.z;
  const int tid = threadIdx.x;
  if (tid == 0) {
    const float* rp = rows + t * 248;
    float s = 0.f, q = 0.f;
    for (int j = 0; j < 64; ++j) {
      s += rp[(h * 4 + j) * 2];
      q += rp[(h * 4 + j) * 2 + 1];
    }
    const float N = 524288.f;
    float mean = s / N;
    float var = q / N - mean * mean;
    float gamma = (t == 0 ? gq[h] : (t == 1 ? gk[h] : gv[h]));
    float beta  = (t == 0 ? beq[h] : (t == 1 ? bek[h] : bev[h]));
    float scale = gamma * rsqrtf(var + 1e-5f);
    ssh[0] = scale;
    ssh[1] = beta - mean * scale;
  }
  __syncthreads();
  const float scale = ssh[0], shift = ssh[1];
  const float* in = proj + (size_t)t * 1048576 + (size_t)(b * 124 + h * 4) * 256;
  const size_t obase = (size_t)(b * 16 + h) * 16384;
  if (t < 2) {
    unsigned short* out = (t == 0 ? outq : outk) + obase;
    for (int sc = 0; sc < 4; ++sc) {
      const int s0 = sc * 64;
      for (int e = tid; e < 1024; e += 256) {
        int g = e >> 4, qq = e & 15;
        float4 val = *(const float4*)(in + g * 256 + s0 + qq * 4);
        T[g][qq * 4 + 0] = val.x * scale + shift;
        T[g][qq * 4 + 1] = val.y * scale + shift;
        T[g][qq * 4 + 2] = val.z * scale + shift;
        T[g][qq * 4 + 3] = val.w * scale + shift;
      }
      __syncthreads();
      for (int e = tid; e < 512; e += 256) {
        int sl = e >> 3, j0 = (e & 7) * 8;
        unsigned int pk[4];
        #pragma unroll
        for (int jj = 0; jj < 4; ++jj) {
          unsigned int a0 = f2b(T[j0 + jj * 2][sl]);
          unsigned int a1 = f2b(T[j0 + jj * 2 + 1][sl]);
          pk[jj] = a0 | (a1 << 16);
        }
        *(uint4*)(out + (s0 + sl) * 64 + j0) = make_uint4(pk[0], pk[1], pk[2], pk[3]);
      }
      __syncthreads();
    }
  } else {
    unsigned short* out = outv + obase;
    for (int e = tid * 4; e < 16384; e += 1024) {
      float4 val = *(const float4*)(in + e);
      unsigned int lo = f2b(val.x * scale + shift) | ((unsigned int)f2b(val.y * scale + shift) << 16);
      unsigned int hi = f2b(val.z * scale + shift) | ((unsigned int)f2b(val.w * scale + shift) << 16);
      *(uint2*)(out + e) = make_uint2(lo, hi);
    }
  }
}

__global__ __launch_bounds__(256) void k_attn(const unsigned short* __restrict__ qwt,
    const unsigned short* __restrict__ kwt, const unsigned short* __restrict__ vwt,
    unsigned short* __restrict__ ob, float* __restrict__ ostats)
{
  __shared__ __align__(16) unsigned short P[4][16 * 256];
  __shared__ float redbuf[8];
  const int h = blockIdx.x, b = blockIdx.y;
  const int bh = b * 16 + h;
  const unsigned short* Q = qwt + (size_t)bh * 16384;
  const unsigned short* K = kwt + (size_t)bh * 16384;
  const unsigned short* V = vwt + (size_t)bh * 16384;
  const int tid = threadIdx.x, w = tid >> 6, l = tid & 63;
  const int lr = l & 15, lg = l >> 4;
  char* Pw = (char*)&P[w][0];
  float s1 = 0.f, s2 = 0.f;
  for (int ch = 0; ch < 4; ++ch) {
    const int i0 = w * 64 + ch * 16;
    short8 qf0 = *(const short8*)(Q + (i0 + lr) * 64 + lg * 8);
    short8 qf1 = *(const short8*)(Q + (i0 + lr) * 64 + 32 + lg * 8);
    f32x4 S[16];
    #pragma unroll
    for (int jt = 0; jt < 16; ++jt) {
      const unsigned short* Kr = K + (jt * 16 + lr) * 64 + lg * 8;
      short8 kf0 = *(const short8*)(Kr);
      short8 kf1 = *(const short8*)(Kr + 32);
      f32x4 a = {0.f, 0.f, 0.f, 0.f};
      a = MFMA16(qf0, kf0, a);
      a = MFMA16(qf1, kf1, a);
      S[jt] = a;
    }
    float mx[4], sm[4], rinv[4];
    #pragma unroll
    for (int r = 0; r < 4; ++r) {
      float m = S[0][r];
      #pragma unroll
      for (int jt = 1; jt < 16; ++jt) m = fmaxf(m, S[jt][r]);
      m = fmaxf(m, __shfl_xor(m, 1));
      m = fmaxf(m, __shfl_xor(m, 2));
      m = fmaxf(m, __shfl_xor(m, 4));
      m = fmaxf(m, __shfl_xor(m, 8));
      mx[r] = m; sm[r] = 0.f;
    }
    #pragma unroll
    for (int jt = 0; jt < 16; ++jt) {
      #pragma unroll
      for (int r = 0; r < 4; ++r) {
        float p = exp2f((S[jt][r] - mx[r]) * 0.18033688011112042f);
        sm[r] += p;
        S[jt][r] = p;
      }
    }
    #pragma unroll
    for (int r = 0; r < 4; ++r) {
      float s = sm[r];
      s += __shfl_xor(s, 1); s += __shfl_xor(s, 2);
      s += __shfl_xor(s, 4); s += __shfl_xor(s, 8);
      rinv[r] = 1.0f / s;
    }
    #pragma unroll
    for (int jt = 0; jt < 16; ++jt) {
      #pragma unroll
      for (int r = 0; r < 4; ++r) {
        int rr = lg * 4 + r;
        int c = jt * 16 + lr;
        int off = rr * 512 + ((c * 2) ^ ((rr & 7) << 4));
        *(unsigned short*)(Pw + off) = f2b(S[jt][r]);
      }
    }
    asm volatile("s_waitcnt lgkmcnt(0)" ::: "memory");
    f32x4 O[4];
    #pragma unroll
    for (int nt = 0; nt < 4; ++nt) O[nt] = (f32x4){0.f, 0.f, 0.f, 0.f};
    #pragma unroll
    for (int js = 0; js < 8; ++js) {
      int off = lr * 512 + (((js * 32 + lg * 8) * 2) ^ ((lr & 7) << 4));
      short8 pf = *(const short8*)(Pw + off);
      #pragma unroll
      for (int nt = 0; nt < 4; ++nt) {
        short8 vf = *(const short8*)(V + (nt * 16 + lr) * 256 + js * 32 + lg * 8);
        O[nt] = MFMA16(pf, vf, O[nt]);
      }
    }
    unsigned short* orow = ob + (size_t)bh * 16384 + (size_t)i0 * 64;
    #pragma unroll
    for (int nt = 0; nt < 4; ++nt) {
      #pragma unroll
      for (int r = 0; r < 4; ++r) {
        float val = O[nt][r] * rinv[r];
        orow[(lg * 4 + r) * 64 + nt * 16 + lr] = f2b(val);
        s1 += val; s2 += val * val;
      }
    }
  }
  #pragma unroll
  for (int m = 1; m < 64; m <<= 1) { s1 += __shfl_xor(s1, m); s2 += __shfl_xor(s2, m); }
  if (l == 0) { redbuf[w * 2] = s1; redbuf[w * 2 + 1] = s2; }
  __syncthreads();
  if (tid == 0) {
    float a = redbuf[0] + redbuf[2] + redbuf[4] + redbuf[6];
    float c = redbuf[1] + redbuf[3] + redbuf[5] + redbuf[7];
    atomicAdd(&ostats[h * 2], a);
    atomicAdd(&ostats[h * 2 + 1], c);
  }
}

// in-place affine on bf16 A; alpha/beta computed inline from ostats
__global__ __launch_bounds__(256) void k_normA(unsigned short* __restrict__ A,
    const float* __restrict__ ostats,
    const float* __restrict__ g1, const float* __restrict__ be1)
{
  __shared__ float oss[32];
  if (threadIdx.x < 16) {
    int h = threadIdx.x;
    const float N = 524288.f;
    float mean = ostats[h * 2] / N;
    float var = ostats[h * 2 + 1] / N - mean * mean;
    float alpha = g1[h] * rsqrtf(var + 1e-5f);
    oss[h * 2] = alpha;
    oss[h * 2 + 1] = be1[h] - mean * alpha;
  }
  __syncthreads();
  int idx = blockIdx.x * 256 + threadIdx.x;
  for (int i = idx; i < 1048576; i += 1024 * 256) {
    int m = i >> 11;
    int hh = m & 15;
    float alpha = oss[hh * 2], beta = oss[hh * 2 + 1];
    uint4 v = ((const uint4*)A)[i];
    unsigned int o0, o1, o2, o3;
    {
      float a = b2f(v.x & 0xffffu) * alpha + beta;
      float b = b2f(v.x >> 16) * alpha + beta;
      o0 = (unsigned int)f2b(a) | ((unsigned int)f2b(b) << 16);
    }
    {
      float a = b2f(v.y & 0xffffu) * alpha + beta;
      float b = b2f(v.y >> 16) * alpha + beta;
      o1 = (unsigned int)f2b(a) | ((unsigned int)f2b(b) << 16);
    }
    {
      float a = b2f(v.z & 0xffffu) * alpha + beta;
      float b = b2f(v.z >> 16) * alpha + beta;
      o2 = (unsigned int)f2b(a) | ((unsigned int)f2b(b) << 16);
    }
    {
      float a = b2f(v.w & 0xffffu) * alpha + beta;
      float b = b2f(v.w >> 16) * alpha + beta;
      o3 = (unsigned int)f2b(a) | ((unsigned int)f2b(b) << 16);
    }
    ((uint4*)A)[i] = make_uint4(o0, o1, o2, o3);
  }
}

// FC1 v12 (best known: 216us): depth-2 counted-vmcnt pipeline, BM=128 BN=128
// BK=64 splitK=8, grid 1280, XCD-coherent bid (ks=bid&7). vmcnt(20) ledger:
// after LOADB(t+2): B(t+1)[8]+A(t+1)[4]+B(t+2)[8]=20 outstanding, drains A(t).
__global__ __launch_bounds__(256) void k_fc1(const unsigned short* __restrict__ Ap,
    const float* __restrict__ W1, float* __restrict__ h1acc)
{
  __shared__ __align__(16) unsigned short As[2][128 * 64];
  __shared__ __align__(16) unsigned short Bs[128 * 64];
  const int bid = blockIdx.x;
  const int ks = bid & 7;
  const int mt = (bid >> 3) & 3;
  const int nt = bid >> 5;
  const int m0 = mt * 128, n0 = nt * 128;
  const int kc = ks * 2048;
  const int tid = threadIdx.x, w = tid >> 6, l = tid & 63;
  const int lr = l & 15, lg = l >> 4;
  const int wr = w >> 1, wc = w & 1;
  const int bn = tid >> 4, bq = tid & 15;
  f32x4 acc[4][4];
  #pragma unroll
  for (int i = 0; i < 4; ++i) {
    #pragma unroll
    for (int j = 0; j < 4; ++j) acc[i][j] = (f32x4){0.f, 0.f, 0.f, 0.f};
  }

#define LOADB(dst, kbase) do { \
  _Pragma("unroll") \
  for (int j_ = 0; j_ < 8; ++j_) { \
    int n_ = j_ * 16 + bn; \
    dst[j_] = (n0 + n_ < 5000) \
      ? *(const float4*)(W1 + (size_t)(n0 + n_) * 16384 + (kbase) + bq * 4) \
      : make_float4(0.f, 0.f, 0.f, 0.f); \
  } } while (0)

#define WRITEB(src) do { \
  _Pragma("unroll") \
  for (int j_ = 0; j_ < 8; ++j_) { \
    int n_ = j_ * 16 + bn; \
    unsigned int lo_ = cvtpk(src[j_].x, src[j_].y); \
    unsigned int hi_ = cvtpk(src[j_].z, src[j_].w); \
    int off_ = (n_ << 7) + ((bq * 8) ^ ((n_ & 7) << 4)); \
    *(uint2*)((char*)Bs + off_) = make_uint2(lo_, hi_); \
  } } while (0)

#define STAGEA(BUFI, kbase) do { \
  char* Ad_ = (char*)&As[BUFI][0]; \
  _Pragma("unroll") \
  for (int it_ = 0; it_ < 4; ++it_) { \
    int p_ = it_ * 4096 + tid * 16; \
    int row_ = p_ >> 7; \
    int cl_ = (p_ & 127) ^ ((row_ & 7) << 4); \
    gload16(Ap + (size_t)(m0 + row_) * 16384 + (kbase) + (cl_ >> 1), Ad_ + p_); \
  } } while (0)

#define COMPUTE(BUFI) do { \
  const char* Ac_ = (const char*)&As[BUFI][0]; \
  __builtin_amdgcn_s_setprio(1); \
  _Pragma("unroll") \
  for (int kh_ = 0; kh_ < 2; ++kh_) { \
    short8 af_[4], bf_[4]; \
    _Pragma("unroll") \
    for (int fi_ = 0; fi_ < 4; ++fi_) { \
      int r_ = wr * 64 + fi_ * 16 + lr; \
      int off_ = (r_ << 7) + ((kh_ * 64 + lg * 16) ^ ((r_ & 7) << 4)); \
      af_[fi_] = *(const short8*)(Ac_ + off_); \
    } \
    _Pragma("unroll") \
    for (int fn_ = 0; fn_ < 4; ++fn_) { \
      int n_ = wc * 64 + fn_ * 16 + lr; \
      int off_ = (n_ << 7) + ((kh_ * 64 + lg * 16) ^ ((n_ & 7) << 4)); \
      bf_[fn_] = *(const short8*)((const char*)Bs + off_); \
    } \
    _Pragma("unroll") \
    for (int fi_ = 0; fi_ < 4; ++fi_) { \
      _Pragma("unroll") \
      for (int fn_ = 0; fn_ < 4; ++fn_) \
        acc[fi_][fn_] = MFMA16(af_[fi_], bf_[fn_], acc[fi_][fn_]); \
    } \
  } \
  __builtin_amdgcn_s_setprio(0); \
  } while (0)

#define ITER(BUFI, WCUR, T) do { \
  const int ka_ = kc + (((T) + 1 < 32) ? ((T) + 1) : 31) * 64; \
  const int kb_ = kc + (((T) + 2 < 32) ? ((T) + 2) : 31) * 64; \
  STAGEA((BUFI) ^ 1, ka_); \
  WRITEB(WCUR); \
  LOADB(WCUR, kb_); \
  asm volatile("s_waitcnt vmcnt(20) lgkmcnt(0)" ::: "memory"); \
  __builtin_amdgcn_s_barrier(); \
  __builtin_amdgcn_sched_barrier(0); \
  COMPUTE(BUFI); \
  __builtin_amdgcn_s_barrier(); \
  __builtin_amdgcn_sched_barrier(0); \
  } while (0)

  float4 wA[8], wB[8];
  // prologue: group order B(0)[8], A(0)[4], B(1)[8] (mirrors steady state)
  LOADB(wA, kc);
  STAGEA(0, kc);
  LOADB(wB, kc + 64);
  for (int th = 0; th < 16; ++th) {
    ITER(0, wA, th * 2);
    ITER(1, wB, th * 2 + 1);
  }

#undef LOADB
#undef WRITEB
#undef STAGEA
#undef COMPUTE
#undef ITER

  #pragma unroll
  for (int fi = 0; fi < 4; ++fi) {
    #pragma unroll
    for (int fn = 0; fn < 4; ++fn) {
      int col = n0 + wc * 64 + fn * 16 + lr;
      if (col < 5000) {
        int rowb = m0 + wr * 64 + fi * 16 + lg * 4;
        #pragma unroll
        for (int r = 0; r < 4; ++r)
          atomicAdd(&h1acc[(size_t)(rowb + r) * 5000 + col], acc[fi][fn][r]);
      }
    }
  }
}

__global__ __launch_bounds__(256) void k_fc1epi(const float* __restrict__ h1acc,
    const float* __restrict__ b1, unsigned short* __restrict__ h1act)
{
  int i = blockIdx.x * 256 + threadIdx.x;
  if (i >= 512 * 1280) return;
  int m = i / 1280;
  int o4 = (i - m * 1280) * 4;
  unsigned int lo = 0, hi = 0;
  if (o4 < 5000) {
    float vv[4];
    #pragma unroll
    for (int j = 0; j < 4; ++j) {
      float x = h1acc[(size_t)m * 5000 + o4 + j] + b1[o4 + j];
      vv[j] = x >= 0.f ? x : 0.01f * x;
    }
    lo = f2b(vv[0]) | ((unsigned int)f2b(vv[1]) << 16);
    hi = f2b(vv[2]) | ((unsigned int)f2b(vv[3]) << 16);
  }
  *(uint2*)(h1act + (size_t)m * 5120 + o4) = make_uint2(lo, hi);
}

// FC2: splitK=16 (5 K-steps of 64 each), grid (16,8)
__global__ __launch_bounds__(256) void k_fc2(const unsigned short* __restrict__ h1act,
    const unsigned short* __restrict__ w2b, float* __restrict__ h2acc)
{
  __shared__ __align__(16) unsigned short As[64 * 64];
  __shared__ __align__(16) unsigned short Bs[64 * 64];
  const int ks = blockIdx.x, mb = blockIdx.y;
  const int m0 = mb * 64;
  const int k0 = ks * 320;
  const int tid = threadIdx.x, w = tid >> 6, l = tid & 63;
  const int lr = l & 15, lg = l >> 4;
  f32x4 acc[4];
  #pragma unroll
  for (int i = 0; i < 4; ++i) acc[i] = (f32x4){0.f, 0.f, 0.f, 0.f};
  for (int st = 0; st < 5; ++st) {
    const int kbase = k0 + st * 64;
    #pragma unroll
    for (int it = 0; it < 2; ++it) {
      int p = it * 4096 + tid * 16;
      int row = p >> 7;
      int colb = (p & 127) ^ ((row & 7) << 4);
      gload16(h1act + (m0 + row) * 5120 + kbase + (colb >> 1), (char*)As + p);
      gload16(w2b + row * 5120 + kbase + (colb >> 1), (char*)Bs + p);
    }
    __syncthreads();
    #pragma unroll
    for (int kh = 0; kh < 2; ++kh) {
      int ar = w * 16 + lr;
      int aoff = (ar << 7) + (((kh * 32 + lg * 8) * 2) ^ ((ar & 7) << 4));
      short8 af = *(const short8*)((char*)As + aoff);
      #pragma unroll
      for (int fn = 0; fn < 4; ++fn) {
        int n = fn * 16 + lr;
        int boff = (n << 7) + (((kh * 32 + lg * 8) * 2) ^ ((n & 7) << 4));
        short8 bf = *(const short8*)((char*)Bs + boff);
        acc[fn] = MFMA16(af, bf, acc[fn]);
      }
    }
    __syncthreads();
  }
  #pragma unroll
  for (int fn = 0; fn < 4; ++fn) {
    int col = fn * 16 + lr;
    int rowb = m0 + w * 16 + lg * 4;
    #pragma unroll
    for (int r = 0; r < 4; ++r)
      atomicAdd(&h2acc[(rowb + r) * 64 + col], acc[fn][r]);
  }
}

__global__ __launch_bounds__(256) void k_final(const float* __restrict__ h2acc,
    const float* __restrict__ b2, float* __restrict__ outp)
{
  int i = blockIdx.x * 256 + threadIdx.x;
  if (i < 32768) {
    float x = h2acc[i] + b2[i & 63];
    outp[i] = 1.f / (1.f + expf(-x));
  }
}

extern "C" void kernel_launch(void* const* d_in, const int* in_sizes, int n_in,
                              void* d_out, int out_size, void* d_ws, size_t ws_size,
                              hipStream_t stream) {
  const float* q   = (const float*)d_in[0];
  const float* kx  = (const float*)d_in[1];
  const float* vx  = (const float*)d_in[2];
  const float* Wq  = (const float*)d_in[3];
  const float* bq  = (const float*)d_in[4];
  const float* Wk  = (const float*)d_in[5];
  const float* bk  = (const float*)d_in[6];
  const float* Wv  = (const float*)d_in[7];
  const float* bv  = (const float*)d_in[8];
  const float* gq  = (const float*)d_in[9];
  const float* gk  = (const float*)d_in[10];
  const float* gv  = (const float*)d_in[11];
  const float* g1  = (const float*)d_in[12];
  const float* beq = (const float*)d_in[13];
  const float* bek = (const float*)d_in[14];
  const float* bev = (const float*)d_in[15];
  const float* be1 = (const float*)d_in[16];
  const float* W1  = (const float*)d_in[17];
  const float* b1  = (const float*)d_in[18];
  const float* W2  = (const float*)d_in[19];
  const float* b2  = (const float*)d_in[20];

  char* ws = (char*)d_ws;
  unsigned short* qwt = (unsigned short*)(ws + OFF_QWT);
  unsigned short* kwt = (unsigned short*)(ws + OFF_KWT);
  unsigned short* vwt = (unsigned short*)(ws + OFF_VWT);
  float* proj   = (float*)(ws + OFF_O);
  unsigned short* Abf = (unsigned short*)(ws + OFF_A);
  float* h1acc  = (float*)(ws + OFF_H1ACC);
  unsigned short* h1act = (unsigned short*)(ws + OFF_H1ACT);
  unsigned short* w2b   = (unsigned short*)(ws + OFF_W2B);
  float* h2acc  = (float*)(ws + OFF_H2ACC);
  float* rows   = (float*)(ws + OFF_ROWS);
  float* ostats = (float*)(ws + OFF_OSTAT);

  k_prep<<<2048, 256, 0, stream>>>(h1acc, 2560000, h2acc, 34944, W2, w2b);
  k_proj3<<<dim3(2, 32, 3), 256, 0, stream>>>(q, kx, vx, Wq, Wk, Wv, bq, bk, bv, proj, rows);
  k_winnorm<<<dim3(16, 32, 3), 256, 0, stream>>>(proj, rows, gq, gk, gv, beq, bek, bev,
                                                 qwt, kwt, vwt);
  k_attn<<<dim3(16, 32), 256, 0, stream>>>(qwt, kwt, vwt, Abf, ostats);
  k_normA<<<1024, 256, 0, stream>>>(Abf, ostats, g1, be1);
  k_fc1<<<1280, 256, 0, stream>>>(Abf, W1, h1acc);
  k_fc1epi<<<2560, 256, 0, stream>>>(h1acc, b1, h1act);
  k_fc2<<<dim3(16, 8), 256, 0, stream>>>(h1act, w2b, h2acc);
  k_final<<<128, 256, 0, stream>>>(h2acc, b2, (float*)d_out);
}